// Round 6
// baseline (198.107 us; speedup 1.0000x reference)
//
#include <hip/hip_runtime.h>

#define NIMG 64
#define H 512
#define W 512

constexpr float THR_64  = 50.0f / 255.0f;          // level_idx=1: 64x64 details
constexpr float THR_128 = 50.0f / 2.0f / 255.0f;   // level_idx=2: 128x128
constexpr float THR_256 = 50.0f / 4.0f / 255.0f;   // level_idx=3: 256x256

__device__ __forceinline__ float wave_sum(float v) {
#pragma unroll
    for (int o = 32; o > 0; o >>= 1) v += __shfl_down(v, o, 64);
    return v;
}

__device__ __forceinline__ float clip01(float x) {
    return fminf(fmaxf(x, 0.0f), 1.0f);
}

__device__ __forceinline__ float4 clip4(float4 p) {
    p.x = clip01(p.x); p.y = clip01(p.y); p.z = clip01(p.z); p.w = clip01(p.w);
    return p;
}

// Per-tile compute (4 rows x 256 cols half): n2v + tv + level-1 + level-2.
// p0..p3 must already be clipped; hl clipped. Pure register arithmetic.
__device__ __forceinline__ void tile_compute(
    float4 p0, float4 p1, float4 p2, float4 p3,
    float4 nz0, float4 nz1, float4 nz2, float4 nz3,
    int4 mk0, int4 mk1, int4 mk2, int4 mk3,
    float4 hl, bool has_halo,
    bool edge, float e0, float e1, float e2, float e3,
    int lane,
    float& n2v, float& msum, float& tv, float& wav1, float& wav2,
    float& ll2v) {
    // --- n2v ---
    float m;
    m = mk0.x ? 1.f : 0.f; n2v += fabsf(p0.x - nz0.x) * m; msum += m;
    m = mk0.y ? 1.f : 0.f; n2v += fabsf(p0.y - nz0.y) * m; msum += m;
    m = mk0.z ? 1.f : 0.f; n2v += fabsf(p0.z - nz0.z) * m; msum += m;
    m = mk0.w ? 1.f : 0.f; n2v += fabsf(p0.w - nz0.w) * m; msum += m;
    m = mk1.x ? 1.f : 0.f; n2v += fabsf(p1.x - nz1.x) * m; msum += m;
    m = mk1.y ? 1.f : 0.f; n2v += fabsf(p1.y - nz1.y) * m; msum += m;
    m = mk1.z ? 1.f : 0.f; n2v += fabsf(p1.z - nz1.z) * m; msum += m;
    m = mk1.w ? 1.f : 0.f; n2v += fabsf(p1.w - nz1.w) * m; msum += m;
    m = mk2.x ? 1.f : 0.f; n2v += fabsf(p2.x - nz2.x) * m; msum += m;
    m = mk2.y ? 1.f : 0.f; n2v += fabsf(p2.y - nz2.y) * m; msum += m;
    m = mk2.z ? 1.f : 0.f; n2v += fabsf(p2.z - nz2.z) * m; msum += m;
    m = mk2.w ? 1.f : 0.f; n2v += fabsf(p2.w - nz2.w) * m; msum += m;
    m = mk3.x ? 1.f : 0.f; n2v += fabsf(p3.x - nz3.x) * m; msum += m;
    m = mk3.y ? 1.f : 0.f; n2v += fabsf(p3.y - nz3.y) * m; msum += m;
    m = mk3.z ? 1.f : 0.f; n2v += fabsf(p3.z - nz3.z) * m; msum += m;
    m = mk3.w ? 1.f : 0.f; n2v += fabsf(p3.w - nz3.w) * m; msum += m;

    // --- TV horizontal interior ---
    tv += fabsf(p0.y - p0.x) + fabsf(p0.z - p0.y) + fabsf(p0.w - p0.z);
    tv += fabsf(p1.y - p1.x) + fabsf(p1.z - p1.y) + fabsf(p1.w - p1.z);
    tv += fabsf(p2.y - p2.x) + fabsf(p2.z - p2.y) + fabsf(p2.w - p2.z);
    tv += fabsf(p3.y - p3.x) + fabsf(p3.z - p3.y) + fabsf(p3.w - p3.z);
    // lane boundary
    float nx0 = __shfl_down(p0.x, 1, 64);
    float nx1 = __shfl_down(p1.x, 1, 64);
    float nx2 = __shfl_down(p2.x, 1, 64);
    float nx3 = __shfl_down(p3.x, 1, 64);
    if (lane < 63) {
        tv += fabsf(nx0 - p0.w) + fabsf(nx1 - p1.w)
            + fabsf(nx2 - p2.w) + fabsf(nx3 - p3.w);
    }
    if (edge) {
        tv += fabsf(e0 - p0.w) + fabsf(e1 - p1.w)
            + fabsf(e2 - p2.w) + fabsf(e3 - p3.w);
    }
    // vertical internal + halo
    tv += fabsf(p1.x - p0.x) + fabsf(p1.y - p0.y) + fabsf(p1.z - p0.z) + fabsf(p1.w - p0.w);
    tv += fabsf(p2.x - p1.x) + fabsf(p2.y - p1.y) + fabsf(p2.z - p1.z) + fabsf(p2.w - p1.w);
    tv += fabsf(p3.x - p2.x) + fabsf(p3.y - p2.y) + fabsf(p3.z - p2.z) + fabsf(p3.w - p2.w);
    if (has_halo) {
        tv += fabsf(p0.x - hl.x) + fabsf(p0.y - hl.y)
            + fabsf(p0.z - hl.z) + fabsf(p0.w - hl.w);
    }

    // --- level-1 Haar: 4 quads ---
    float a, b, c, d, ch, cv, cd;
    a = p0.x; b = p0.y; c = p1.x; d = p1.y;
    float llA0 = (a + b + c + d) * 0.5f;
    ch = (a + b - c - d) * 0.5f; cv = (a - b + c - d) * 0.5f; cd = (a - b - c + d) * 0.5f;
    wav1 += fminf(fabsf(ch), THR_256) + fminf(fabsf(cv), THR_256) + fminf(fabsf(cd), THR_256);
    a = p0.z; b = p0.w; c = p1.z; d = p1.w;
    float llA1 = (a + b + c + d) * 0.5f;
    ch = (a + b - c - d) * 0.5f; cv = (a - b + c - d) * 0.5f; cd = (a - b - c + d) * 0.5f;
    wav1 += fminf(fabsf(ch), THR_256) + fminf(fabsf(cv), THR_256) + fminf(fabsf(cd), THR_256);
    a = p2.x; b = p2.y; c = p3.x; d = p3.y;
    float llB0 = (a + b + c + d) * 0.5f;
    ch = (a + b - c - d) * 0.5f; cv = (a - b + c - d) * 0.5f; cd = (a - b - c + d) * 0.5f;
    wav1 += fminf(fabsf(ch), THR_256) + fminf(fabsf(cv), THR_256) + fminf(fabsf(cd), THR_256);
    a = p2.z; b = p2.w; c = p3.z; d = p3.w;
    float llB1 = (a + b + c + d) * 0.5f;
    ch = (a + b - c - d) * 0.5f; cv = (a - b + c - d) * 0.5f; cd = (a - b - c + d) * 0.5f;
    wav1 += fminf(fabsf(ch), THR_256) + fminf(fabsf(cv), THR_256) + fminf(fabsf(cd), THR_256);

    // --- level-2 Haar: lane-local quad ---
    a = llA0; b = llA1; c = llB0; d = llB1;
    ll2v = (a + b + c + d) * 0.5f;
    ch = (a + b - c - d) * 0.5f;
    cv = (a - b + c - d) * 0.5f;
    cd = (a - b - c + d) * 0.5f;
    wav2 += fminf(fabsf(ch), THR_128) + fminf(fabsf(cv), THR_128) + fminf(fabsf(cd), THR_128);
}

// Kernel A: software-pipelined two-tile wave. Wave = rows [8Q, 8Q+8) x 256-col
// half; all 25 A+B loads issued before any consume, so B's 12 loads stay in
// flight while A computes. B's halo = A's row 3 (in-register). No atomics.
// Grid = 8192 waves / 4 = 2048 blocks (exactly 32 waves/CU of work per round).
__global__ __launch_bounds__(256, 4) void kA(const float* __restrict__ pred,
                                             const float* __restrict__ noisy,
                                             const int* __restrict__ mask,
                                             float4* __restrict__ pA,
                                             float* __restrict__ pW2,
                                             float* __restrict__ ll2) {
    __shared__ float red[4][5];

    const int tid = threadIdx.x;
    const int lane = tid & 63;
    const int wv = tid >> 6;
    const int w = (blockIdx.x << 2) + wv;      // 0..8191
    const int n = w >> 7;                      // image
    const int rem = w & 127;
    const int Q = rem >> 1;                    // 8-row tile 0..63
    const int h = rem & 1;                     // 256-col half
    const int r0 = Q << 3;
    const int col = (h << 8) + (lane << 2);
    const size_t base = (size_t)n * (H * W) + (size_t)r0 * W + col;
    const bool haloA = (Q > 0);                // wave-uniform
    const size_t baseH = haloA ? (base - W) : base;   // clamped (term zeroed)
    const bool edge = (h == 0) && (lane == 63);

    // ---------------- load cluster: 25 independent vector loads ----------------
    float4 a_p0 = *reinterpret_cast<const float4*>(pred + base);
    float4 a_p1 = *reinterpret_cast<const float4*>(pred + base + W);
    float4 a_p2 = *reinterpret_cast<const float4*>(pred + base + 2 * W);
    float4 a_p3 = *reinterpret_cast<const float4*>(pred + base + 3 * W);
    float4 b_p0 = *reinterpret_cast<const float4*>(pred + base + 4 * W);
    float4 b_p1 = *reinterpret_cast<const float4*>(pred + base + 5 * W);
    float4 b_p2 = *reinterpret_cast<const float4*>(pred + base + 6 * W);
    float4 b_p3 = *reinterpret_cast<const float4*>(pred + base + 7 * W);
    float4 a_hl = *reinterpret_cast<const float4*>(pred + baseH);
    float4 a_nz0 = *reinterpret_cast<const float4*>(noisy + base);
    float4 a_nz1 = *reinterpret_cast<const float4*>(noisy + base + W);
    float4 a_nz2 = *reinterpret_cast<const float4*>(noisy + base + 2 * W);
    float4 a_nz3 = *reinterpret_cast<const float4*>(noisy + base + 3 * W);
    float4 b_nz0 = *reinterpret_cast<const float4*>(noisy + base + 4 * W);
    float4 b_nz1 = *reinterpret_cast<const float4*>(noisy + base + 5 * W);
    float4 b_nz2 = *reinterpret_cast<const float4*>(noisy + base + 6 * W);
    float4 b_nz3 = *reinterpret_cast<const float4*>(noisy + base + 7 * W);
    int4 a_mk0 = *reinterpret_cast<const int4*>(mask + base);
    int4 a_mk1 = *reinterpret_cast<const int4*>(mask + base + W);
    int4 a_mk2 = *reinterpret_cast<const int4*>(mask + base + 2 * W);
    int4 a_mk3 = *reinterpret_cast<const int4*>(mask + base + 3 * W);
    int4 b_mk0 = *reinterpret_cast<const int4*>(mask + base + 4 * W);
    int4 b_mk1 = *reinterpret_cast<const int4*>(mask + base + 5 * W);
    int4 b_mk2 = *reinterpret_cast<const int4*>(mask + base + 6 * W);
    int4 b_mk3 = *reinterpret_cast<const int4*>(mask + base + 7 * W);
    // seam col 255|256 (left half, lane 63 only): 8 predicated scalar loads
    float ea0 = 0.f, ea1 = 0.f, ea2 = 0.f, ea3 = 0.f;
    float eb0 = 0.f, eb1 = 0.f, eb2 = 0.f, eb3 = 0.f;
    if (edge) {
        ea0 = pred[base + 4];          ea1 = pred[base + W + 4];
        ea2 = pred[base + 2 * W + 4];  ea3 = pred[base + 3 * W + 4];
        eb0 = pred[base + 4 * W + 4];  eb1 = pred[base + 5 * W + 4];
        eb2 = pred[base + 6 * W + 4];  eb3 = pred[base + 7 * W + 4];
    }

    // ---------------- consume tile A (B loads still in flight) ----------------
    a_p0 = clip4(a_p0); a_p1 = clip4(a_p1); a_p2 = clip4(a_p2); a_p3 = clip4(a_p3);
    a_hl = clip4(a_hl);
    ea0 = clip01(ea0); ea1 = clip01(ea1); ea2 = clip01(ea2); ea3 = clip01(ea3);

    float n2v = 0.f, msum = 0.f, tv = 0.f, wav1 = 0.f, wav2 = 0.f;
    float ll2A, ll2B;
    tile_compute(a_p0, a_p1, a_p2, a_p3,
                 a_nz0, a_nz1, a_nz2, a_nz3,
                 a_mk0, a_mk1, a_mk2, a_mk3,
                 a_hl, haloA, edge, ea0, ea1, ea2, ea3, lane,
                 n2v, msum, tv, wav1, wav2, ll2A);

    // ---------------- consume tile B (halo = A row 3, in-register) ----------------
    b_p0 = clip4(b_p0); b_p1 = clip4(b_p1); b_p2 = clip4(b_p2); b_p3 = clip4(b_p3);
    eb0 = clip01(eb0); eb1 = clip01(eb1); eb2 = clip01(eb2); eb3 = clip01(eb3);
    tile_compute(b_p0, b_p1, b_p2, b_p3,
                 b_nz0, b_nz1, b_nz2, b_nz3,
                 b_mk0, b_mk1, b_mk2, b_mk3,
                 a_p3, true, edge, eb0, eb1, eb2, eb3, lane,
                 n2v, msum, tv, wav1, wav2, ll2B);

    // LL2 rows 2Q (tile A) and 2Q+1 (tile B), col 64h+lane
    {
        float* dst = ll2 + (size_t)n * 16384 + (size_t)(Q << 1) * 128 + (h << 6) + lane;
        dst[0] = ll2A;
        dst[128] = ll2B;
    }

    // --- block reduction -> plain stores ---
    float v0 = wave_sum(n2v);
    float v1 = wave_sum(msum);
    float v2 = wave_sum(tv);
    float v3 = wave_sum(wav1);
    float v4 = wave_sum(wav2);
    if (lane == 0) {
        red[wv][0] = v0; red[wv][1] = v1; red[wv][2] = v2;
        red[wv][3] = v3; red[wv][4] = v4;
    }
    __syncthreads();
    if (tid == 0) {
        pA[blockIdx.x] = make_float4(red[0][0] + red[1][0] + red[2][0] + red[3][0],
                                     red[0][1] + red[1][1] + red[2][1] + red[3][1],
                                     red[0][2] + red[1][2] + red[2][2] + red[3][2],
                                     red[0][3] + red[1][3] + red[2][3] + red[3][3]);
        pW2[blockIdx.x] = red[0][4] + red[1][4] + red[2][4] + red[3][4];
    }
}

// Kernel C: level-3 details from LL2 (64x128x128, 4 MB). Grid = 128 blocks,
// 8 quads/thread. Partials to pC[bid].
__global__ __launch_bounds__(256) void kC(const float* __restrict__ ll2,
                                          float* __restrict__ pC) {
    __shared__ float red[4];
    const int tid = threadIdx.x;
    const int lane = tid & 63, wv = tid >> 6;
    const int bid = blockIdx.x;
    const int n = bid >> 1;
    const int s = bid & 1;                      // quad-row half [32s, 32s+32)
    const float* src = ll2 + (size_t)n * 16384;

    float wav3 = 0.0f;
#pragma unroll
    for (int i = 0; i < 8; ++i) {
        int u = (i << 8) + tid;                 // 0..2047
        int qr = (s << 5) + (u >> 6);           // 0..63
        int qc = u & 63;
        float2 top = *reinterpret_cast<const float2*>(src + (2 * qr) * 128 + 2 * qc);
        float2 bot = *reinterpret_cast<const float2*>(src + (2 * qr + 1) * 128 + 2 * qc);
        float a = top.x, b = top.y, c = bot.x, d = bot.y;
        float ch = (a + b - c - d) * 0.5f;
        float cv = (a - b + c - d) * 0.5f;
        float cd = (a - b - c + d) * 0.5f;
        wav3 += fminf(fabsf(ch), THR_64) + fminf(fabsf(cv), THR_64) + fminf(fabsf(cd), THR_64);
    }
    float v = wave_sum(wav3);
    if (lane == 0) red[wv] = v;
    __syncthreads();
    if (tid == 0) pC[bid] = red[0] + red[1] + red[2] + red[3];
}

// Kernel D: reduce partials (2048 float4 + 2048 float + 128 float), compose.
__global__ __launch_bounds__(256) void kD(const float4* __restrict__ pA,
                                          const float* __restrict__ pW2,
                                          const float* __restrict__ pC,
                                          float* __restrict__ out) {
    __shared__ float red[4][6];
    const int tid = threadIdx.x;
    const int lane = tid & 63, wv = tid >> 6;

    float s0 = 0, s1 = 0, s2 = 0, s3 = 0, s4 = 0, s5 = 0;
#pragma unroll
    for (int j = 0; j < 8; ++j) {
        float4 v = pA[tid + (j << 8)];
        s0 += v.x; s1 += v.y; s2 += v.z; s3 += v.w;
        s4 += pW2[tid + (j << 8)];
    }
    if (tid < 128) s5 = pC[tid];

    s0 = wave_sum(s0); s1 = wave_sum(s1); s2 = wave_sum(s2);
    s3 = wave_sum(s3); s4 = wave_sum(s4); s5 = wave_sum(s5);
    if (lane == 0) {
        red[wv][0] = s0; red[wv][1] = s1; red[wv][2] = s2;
        red[wv][3] = s3; red[wv][4] = s4; red[wv][5] = s5;
    }
    __syncthreads();
    if (tid == 0) {
        float a0 = red[0][0] + red[1][0] + red[2][0] + red[3][0];
        float a1 = red[0][1] + red[1][1] + red[2][1] + red[3][1];
        float a2 = red[0][2] + red[1][2] + red[2][2] + red[3][2];
        float a3 = red[0][3] + red[1][3] + red[2][3] + red[3][3];
        float a4 = red[0][4] + red[1][4] + red[2][4] + red[3][4];
        float a5 = red[0][5] + red[1][5] + red[2][5] + red[3][5];
        float n2v = a0 / fmaxf(a1, 1.0f);
        float tv = a2 / 16744448.0f;                   // 64*511*512 (both terms)
        float wav = a3 * (1.0f / 37748736.0f)          // (1/3) / (3*64*256*256)
                  + a4 * (1.0f / 6291456.0f)           // (1/2) / (3*64*128*128)
                  + a5 * (1.0f / 786432.0f);           // 1     / (3*64*64*64)
        out[0] = 1.0f * n2v + 0.2f * wav + 0.01f * tv;
    }
}

extern "C" void kernel_launch(void* const* d_in, const int* in_sizes, int n_in,
                              void* d_out, int out_size, void* d_ws, size_t ws_size,
                              hipStream_t stream) {
    (void)in_sizes; (void)n_in; (void)out_size; (void)ws_size;
    const float* pred  = (const float*)d_in[0];
    const float* noisy = (const float*)d_in[1];
    const int*   mask  = (const int*)d_in[2];

    float4* pA  = (float4*)d_ws;                          // 2048 * 16 B = 32 KB
    float*  pW2 = (float*)((char*)d_ws + 32768);          // 2048 * 4 B = 8 KB
    float*  pC  = (float*)((char*)d_ws + 40960);          // 128 * 4 B
    float*  ll2 = (float*)((char*)d_ws + 49152);          // 64*128*128 floats = 4 MB

    kA<<<2048, 256, 0, stream>>>(pred, noisy, mask, pA, pW2, ll2);
    kC<<<128, 256, 0, stream>>>(ll2, pC);
    kD<<<1, 256, 0, stream>>>(pA, pW2, pC, (float*)d_out);
}